// Round 8
// baseline (191.103 us; speedup 1.0000x reference)
//
#include <hip/hip_runtime.h>
#include <math.h>

typedef __attribute__((ext_vector_type(8))) short short8;
typedef __attribute__((ext_vector_type(4))) float f32x4;

#define B_  16
#define T_  4096
#define C_  64
#define KE_ 1023
#define BT_ (B_ * T_)
#define WINDOW 1e-3f   // guard band >= 3x provable bf16-split distance error

// ---------------- ws layout (bytes) ----------------
// [64,      4160)    float ee[1024]        (|e_k|^2, ee[1023]=+inf pad)
// [4224,    135296)  u16   Eh[1024*64]     (bf16 hi of codebook[1:])
// [135296,  266368)  u16   El[1024*64]     (bf16 lo residual)
// [266368,  528512)  int   kbest[BT]
// [528512,  790656)  int   selpos[BT]
// [790656,  790720)  int   nst[B]
// [791680,  793728)  float commit_part[512]
// [793728,  795776)  float valid_part[512]
// [795776,  797888)  float smooth_part[528]   (512 in-block + 16 boundary)

__device__ __forceinline__ unsigned short f2bf(float x) {
    unsigned int u = __float_as_uint(x);
    unsigned int r = (u + 0x7FFFu + ((u >> 16) & 1u)) >> 16;   // RNE
    return (unsigned short)r;
}
__device__ __forceinline__ float bf2f(unsigned short h) {
    return __uint_as_float(((unsigned int)h) << 16);
}

// ---- prep: ee, bf16 hi/lo codebook ----
__global__ __launch_bounds__(256) void k_prep(const float* __restrict__ cb,
                                              float* __restrict__ ee,
                                              unsigned short* __restrict__ Eh,
                                              unsigned short* __restrict__ El) {
    const int k = blockIdx.x * 256 + threadIdx.x;   // 0..1023
    unsigned int* EhU = (unsigned int*)Eh;
    unsigned int* ElU = (unsigned int*)El;
    if (k < KE_) {
        const float* r = cb + (size_t)(k + 1) * C_;
        float s = 0.f;
        #pragma unroll
        for (int c = 0; c < C_; c += 2) {
            const float x0 = r[c], x1 = r[c + 1];
            s = fmaf(x0, x0, s);
            s = fmaf(x1, x1, s);
            const unsigned short h0 = f2bf(x0), h1 = f2bf(x1);
            const unsigned short l0 = f2bf(x0 - bf2f(h0));
            const unsigned short l1 = f2bf(x1 - bf2f(h1));
            EhU[k * 32 + c / 2] = (unsigned int)h0 | ((unsigned int)h1 << 16);
            ElU[k * 32 + c / 2] = (unsigned int)l0 | ((unsigned int)l1 << 16);
        }
        ee[k] = s;
    } else {        // k == 1023 pad: zero rows, inf distance
        #pragma unroll
        for (int c = 0; c < 32; ++c) { EhU[k * 32 + c] = 0u; ElU[k * 32 + c] = 0u; }
        ee[k] = INFINITY;
    }
}

// ---- mega-kernel: MFMA argmin + guard + in-block exact rescan + epilogue ----
// 512 blocks x 128 queries. Phase 1: verified R6 bf16 hi/lo MFMA top-2 scan.
// Phase 2: flagged queries rescanned exactly in-block (verified k_fix chain).
// Phase 3: thread-pair epilogue (z_q, commit, valid, 127 in-block smooth
// pairs via LDS staging aliased over the dead MFMA tiles).
__global__ __launch_bounds__(256, 4) void k_assign(
    const float* __restrict__ z, const float* __restrict__ cb,
    const unsigned short* __restrict__ Eh, const unsigned short* __restrict__ El,
    const float* __restrict__ ee, const float* __restrict__ mask,
    int* __restrict__ kbest, float* __restrict__ zqo,
    float* __restrict__ commit_part, float* __restrict__ valid_part,
    float* __restrict__ smooth_part) {

    __shared__ __align__(16) char smem[37376];   // phase1: Eh|El|ee tiles; phase3: z_q
    unsigned short* s_eh = (unsigned short*)smem;            // 18432 B
    unsigned short* s_el = (unsigned short*)(smem + 18432);  // 18432 B
    float*          s_ee = (float*)(smem + 36864);           // 512 B
    float*          s_zq = (float*)smem;                     // phase-3 alias, 32768 B

    __shared__ int   s_kb[128];
    __shared__ int   s_flist[128];
    __shared__ int   s_fcnt;
    __shared__ float s_z[64];
    __shared__ float s_bv[4];
    __shared__ int   s_bk[4];
    __shared__ float s_red[12];

    const int tid  = threadIdx.x;
    const int wave = tid >> 6;
    const int lane = tid & 63;
    const int col  = lane & 15;
    const int quad = lane >> 4;
    const int B0   = blockIdx.x * 128;
    const int Q0   = B0 + wave * 32;

    if (tid == 0) s_fcnt = 0;

    // ---- phase 1: A-frags (normalize + bf16 hi/lo split, in-register) ----
    short8 ah[2][2], al[2][2];
    #pragma unroll
    for (int g = 0; g < 2; ++g) {
        const float4* zp = (const float4*)(z + (size_t)(Q0 + g * 16 + col) * C_);
        const float4 f0 = zp[quad * 2];
        const float4 f1 = zp[quad * 2 + 1];
        const float4 f2 = zp[8 + quad * 2];
        const float4 f3 = zp[8 + quad * 2 + 1];
        float xs[16] = {f0.x, f0.y, f0.z, f0.w, f1.x, f1.y, f1.z, f1.w,
                        f2.x, f2.y, f2.z, f2.w, f3.x, f3.y, f3.z, f3.w};
        float ss = 0.f;
        #pragma unroll
        for (int i = 0; i < 16; ++i) ss = fmaf(xs[i], xs[i], ss);
        ss += __shfl_xor(ss, 16);
        ss += __shfl_xor(ss, 32);
        const float inv = 1.f / fmaxf(sqrtf(ss), 1e-12f);
        short8 h0, h1, l0, l1;
        #pragma unroll
        for (int i = 0; i < 8; ++i) {
            const float x = xs[i] * inv;
            const unsigned short hx = f2bf(x);
            h0[i] = (short)hx;
            l0[i] = (short)f2bf(x - bf2f(hx));
            const float y = xs[8 + i] * inv;
            const unsigned short hy = f2bf(y);
            h1[i] = (short)hy;
            l1[i] = (short)f2bf(y - bf2f(hy));
        }
        ah[g][0] = h0; ah[g][1] = h1;
        al[g][0] = l0; al[g][1] = l1;
    }

    float bestv[2][4], secv[2][4];
    int   bkk[2][4];
    #pragma unroll
    for (int g = 0; g < 2; ++g)
        #pragma unroll
        for (int r = 0; r < 4; ++r) {
            bestv[g][r] = INFINITY; secv[g][r] = INFINITY; bkk[g][r] = 0;
        }

    for (int t = 0; t < 8; ++t) {
        __syncthreads();
        #pragma unroll
        for (int j = 0; j < 4; ++j) {
            const int p   = j * 256 + tid;
            const int row = p >> 3;
            const int pc  = p & 7;
            *(uint4*)(&s_eh[row * 72 + pc * 8]) =
                *(const uint4*)(&Eh[(size_t)(t * 128 + row) * 64 + pc * 8]);
            *(uint4*)(&s_el[row * 72 + pc * 8]) =
                *(const uint4*)(&El[(size_t)(t * 128 + row) * 64 + pc * 8]);
        }
        if (tid < 128) s_ee[tid] = ee[t * 128 + tid];
        __syncthreads();

        #pragma unroll 2
        for (int s = 0; s < 8; ++s) {
            const int rbase = (s * 16 + col) * 72 + quad * 8;
            const short8 bh0 = *(const short8*)(&s_eh[rbase]);
            const short8 bh1 = *(const short8*)(&s_eh[rbase + 32]);
            const short8 bl0 = *(const short8*)(&s_el[rbase]);
            const short8 bl1 = *(const short8*)(&s_el[rbase + 32]);
            const float  eev = s_ee[s * 16 + col];

            f32x4 p0 = {0.f, 0.f, 0.f, 0.f}, q0 = {0.f, 0.f, 0.f, 0.f};
            f32x4 p1 = {0.f, 0.f, 0.f, 0.f}, q1 = {0.f, 0.f, 0.f, 0.f};
            p0 = __builtin_amdgcn_mfma_f32_16x16x32_bf16(ah[0][0], bh0, p0, 0, 0, 0);
            p1 = __builtin_amdgcn_mfma_f32_16x16x32_bf16(ah[1][0], bh0, p1, 0, 0, 0);
            q0 = __builtin_amdgcn_mfma_f32_16x16x32_bf16(ah[0][1], bh1, q0, 0, 0, 0);
            q1 = __builtin_amdgcn_mfma_f32_16x16x32_bf16(ah[1][1], bh1, q1, 0, 0, 0);
            p0 = __builtin_amdgcn_mfma_f32_16x16x32_bf16(ah[0][0], bl0, p0, 0, 0, 0);
            p1 = __builtin_amdgcn_mfma_f32_16x16x32_bf16(ah[1][0], bl0, p1, 0, 0, 0);
            q0 = __builtin_amdgcn_mfma_f32_16x16x32_bf16(ah[0][1], bl1, q0, 0, 0, 0);
            q1 = __builtin_amdgcn_mfma_f32_16x16x32_bf16(ah[1][1], bl1, q1, 0, 0, 0);
            p0 = __builtin_amdgcn_mfma_f32_16x16x32_bf16(al[0][0], bh0, p0, 0, 0, 0);
            p1 = __builtin_amdgcn_mfma_f32_16x16x32_bf16(al[1][0], bh0, p1, 0, 0, 0);
            q0 = __builtin_amdgcn_mfma_f32_16x16x32_bf16(al[0][1], bh1, q0, 0, 0, 0);
            q1 = __builtin_amdgcn_mfma_f32_16x16x32_bf16(al[1][1], bh1, q1, 0, 0, 0);

            const int kc = t * 128 + s * 16 + col;
            #pragma unroll
            for (int r = 0; r < 4; ++r) {
                {
                    const float v = fmaf(-2.f, p0[r] + q0[r], eev);
                    const bool lt = v < bestv[0][r];
                    secv[0][r]  = lt ? bestv[0][r] : fminf(secv[0][r], v);
                    bkk[0][r]   = lt ? kc : bkk[0][r];
                    bestv[0][r] = lt ? v : bestv[0][r];
                }
                {
                    const float v = fmaf(-2.f, p1[r] + q1[r], eev);
                    const bool lt = v < bestv[1][r];
                    secv[1][r]  = lt ? bestv[1][r] : fminf(secv[1][r], v);
                    bkk[1][r]   = lt ? kc : bkk[1][r];
                    bestv[1][r] = lt ? v : bestv[1][r];
                }
            }
        }
    }

    // ---- top-2 merge; winners + ambiguity flags into LDS ----
    #pragma unroll
    for (int g = 0; g < 2; ++g) {
        #pragma unroll
        for (int r = 0; r < 4; ++r) {
            float b  = bestv[g][r], sc = secv[g][r];
            int   k  = bkk[g][r];
            #pragma unroll
            for (int off = 1; off < 16; off <<= 1) {
                const float ob = __shfl_xor(b, off);
                const int   ok = __shfl_xor(k, off);
                const float os = __shfl_xor(sc, off);
                const bool take = (ob < b) || (ob == b && ok < k);
                const float lose = take ? b : ob;
                sc = fminf(fminf(sc, os), lose);
                b  = take ? ob : b;
                k  = take ? ok : k;
            }
            if (col == 0) {
                const int jl = wave * 32 + g * 16 + quad * 4 + r;
                s_kb[jl] = k;
                if (!(sc - b > WINDOW)) {             // ambiguous -> exact path
                    const int pos = atomicAdd(&s_fcnt, 1);
                    s_flist[pos] = jl;
                }
            }
        }
    }
    __syncthreads();

    // ---- phase 2: exact fp32 rescan of flagged queries (verified chain) ----
    const int nflag = s_fcnt;
    for (int i = 0; i < nflag; ++i) {
        const int jl = s_flist[i];
        const int q  = B0 + jl;
        __syncthreads();               // protect s_z / s_bv reuse
        if (tid < 16) ((float4*)s_z)[tid] = ((const float4*)(z + (size_t)q * C_))[tid];
        __syncthreads();

        float4 zn[16];
        float ss = 0.f;
        #pragma unroll
        for (int c4 = 0; c4 < 16; ++c4) {
            const float4 v = ((const float4*)s_z)[c4];
            zn[c4] = v;
            ss = fmaf(v.x, v.x, ss); ss = fmaf(v.y, v.y, ss);
            ss = fmaf(v.z, v.z, ss); ss = fmaf(v.w, v.w, ss);
        }
        const float nrm = fmaxf(sqrtf(ss), 1e-12f);
        #pragma unroll
        for (int c4 = 0; c4 < 16; ++c4) {
            zn[c4].x /= nrm; zn[c4].y /= nrm; zn[c4].z /= nrm; zn[c4].w /= nrm;
        }

        const int k0 = tid * 4;
        const float4* e0 = (const float4*)(cb + (size_t)(k0 + 1) * C_);
        const float4* e1 = (const float4*)(cb + (size_t)(k0 + 2) * C_);
        const float4* e2 = (const float4*)(cb + (size_t)(k0 + 3) * C_);
        const float4* e3 = (const float4*)(cb + (size_t)((k0 + 4 <= KE_) ? (k0 + 4) : KE_) * C_);
        float d0 = 0.f, d1 = 0.f, d2 = 0.f, d3 = 0.f;
        #pragma unroll
        for (int c4 = 0; c4 < 16; ++c4) {   // in-order fp32 chains
            const float4 x = zn[c4];
            const float4 a = e0[c4], b = e1[c4], c = e2[c4], d = e3[c4];
            d0 = fmaf(x.x, a.x, d0); d0 = fmaf(x.y, a.y, d0);
            d0 = fmaf(x.z, a.z, d0); d0 = fmaf(x.w, a.w, d0);
            d1 = fmaf(x.x, b.x, d1); d1 = fmaf(x.y, b.y, d1);
            d1 = fmaf(x.z, b.z, d1); d1 = fmaf(x.w, b.w, d1);
            d2 = fmaf(x.x, c.x, d2); d2 = fmaf(x.y, c.y, d2);
            d2 = fmaf(x.z, c.z, d2); d2 = fmaf(x.w, c.w, d2);
            d3 = fmaf(x.x, d.x, d3); d3 = fmaf(x.y, d.y, d3);
            d3 = fmaf(x.z, d.z, d3); d3 = fmaf(x.w, d.w, d3);
        }
        float bv = INFINITY;
        int   bk = 0;
        float v;
        v = fmaf(-2.f, d0, ee[k0 + 0]); if (v < bv) { bv = v; bk = k0 + 0; }
        v = fmaf(-2.f, d1, ee[k0 + 1]); if (v < bv) { bv = v; bk = k0 + 1; }
        v = fmaf(-2.f, d2, ee[k0 + 2]); if (v < bv) { bv = v; bk = k0 + 2; }
        v = fmaf(-2.f, d3, ee[k0 + 3]); if (v < bv) { bv = v; bk = k0 + 3; }

        #pragma unroll
        for (int off = 32; off > 0; off >>= 1) {
            const float ov = __shfl_down(bv, off);
            const int   ok = __shfl_down(bk, off);
            if (ov < bv || (ov == bv && ok < bk)) { bv = ov; bk = ok; }
        }
        if (lane == 0) { s_bv[wave] = bv; s_bk[wave] = bk; }
        __syncthreads();
        if (tid == 0) {
            float fb = s_bv[0]; int fk = s_bk[0];
            #pragma unroll
            for (int w = 1; w < 4; ++w) {
                if (s_bv[w] < fb || (s_bv[w] == fb && s_bk[w] < fk)) {
                    fb = s_bv[w]; fk = s_bk[w];
                }
            }
            s_kb[jl] = fk;
        }
    }
    __syncthreads();   // s_kb final; MFMA tiles dead -> s_zq alias safe

    // ---- phase 3: thread-pair epilogue (q = B0 + tid/2, half = tid&1) ----
    if (tid < 128) kbest[B0 + tid] = s_kb[tid];

    const int jq   = tid >> 1;
    const int half = tid & 1;
    const int q    = B0 + jq;
    const int bi   = s_kb[jq];
    const float m  = mask[q];
    const float mnext = (jq < 127) ? mask[q + 1] : 0.f;

    const float4* zp = (const float4*)(z + (size_t)q * C_) + half * 8;
    const float4* er = (const float4*)(cb + (size_t)(bi + 1) * C_) + half * 8;
    float4* zo = (float4*)(zqo + (size_t)q * C_) + half * 8;

    float4 zr[8];
    float ss = 0.f;
    #pragma unroll
    for (int i = 0; i < 8; ++i) {
        const float4 v = zp[i];
        zr[i] = v;
        ss = fmaf(v.x, v.x, ss); ss = fmaf(v.y, v.y, ss);
        ss = fmaf(v.z, v.z, ss); ss = fmaf(v.w, v.w, ss);
    }
    ss += __shfl_xor(ss, 1);
    const float nrm = fmaxf(sqrtf(ss), 1e-12f);

    float commit = 0.f;
    float4 ov[8];
    #pragma unroll
    for (int i = 0; i < 8; ++i) {
        const float z0 = zr[i].x / nrm, z1 = zr[i].y / nrm;
        const float z2 = zr[i].z / nrm, z3 = zr[i].w / nrm;
        const float4 e4 = er[i];
        const float q0 = e4.x * m, q1 = e4.y * m, q2 = e4.z * m, q3 = e4.w * m;
        float4 o;
        o.x = (z0 + q0) - z0;              // straight-through forward value
        o.y = (z1 + q1) - z1;
        o.z = (z2 + q2) - z2;
        o.w = (z3 + q3) - z3;
        ov[i] = o;
        zo[i] = o;
        ((float4*)s_zq)[jq * 16 + half * 8 + i] = o;
        const float d0 = z0 - q0, d1 = z1 - q1, d2 = z2 - q2, d3 = z3 - q3;
        commit = fmaf(d0, d0, commit); commit = fmaf(d1, d1, commit);
        commit = fmaf(d2, d2, commit); commit = fmaf(d3, d3, commit);
    }
    commit *= m;
    __syncthreads();   // s_zq complete

    float sm = 0.f;
    if (jq < 127) {
        #pragma unroll
        for (int i = 0; i < 8; ++i) {
            const float4 nb = ((const float4*)s_zq)[(jq + 1) * 16 + half * 8 + i];
            const float x0 = ov[i].x - nb.x, x1 = ov[i].y - nb.y;
            const float x2 = ov[i].z - nb.z, x3 = ov[i].w - nb.w;
            sm = fmaf(x0, x0, sm); sm = fmaf(x1, x1, sm);
            sm = fmaf(x2, x2, sm); sm = fmaf(x3, x3, sm);
        }
        sm *= mnext;
    }
    float vc = (half == 0) ? m : 0.f;

    #pragma unroll
    for (int off = 32; off > 0; off >>= 1) {
        commit += __shfl_down(commit, off);
        vc     += __shfl_down(vc, off);
        sm     += __shfl_down(sm, off);
    }
    if (lane == 0) { s_red[wave] = commit; s_red[4 + wave] = vc; s_red[8 + wave] = sm; }
    __syncthreads();
    if (tid == 0) {
        commit_part[blockIdx.x] = s_red[0] + s_red[1] + s_red[2] + s_red[3];
        valid_part[blockIdx.x]  = s_red[4] + s_red[5] + s_red[6] + s_red[7];
        smooth_part[blockIdx.x] = s_red[8] + s_red[9] + s_red[10] + s_red[11];
    }
}

// ---- per-batch start compaction + block-boundary smoothness pairs ----
__global__ __launch_bounds__(256) void k_scan(const int* __restrict__ kbest,
                                              const float* __restrict__ mask,
                                              const float* __restrict__ zqo,
                                              int* __restrict__ selpos,
                                              int* __restrict__ nst,
                                              float* __restrict__ smooth_part) {
    __shared__ int cnt[256];
    __shared__ float sred[4];
    const int b = blockIdx.x;
    const int tid = threadIdx.x;
    const int base = b * T_;
    const int t0 = tid * 16;

    int flags = 0, c = 0;
    int prev = (tid == 0) ? -1 : kbest[base + t0 - 1];
    #pragma unroll
    for (int i = 0; i < 16; ++i) {
        const int t = t0 + i;
        const int cur = kbest[base + t];
        const int is = (t == 0) ? 1
                     : ((cur != prev && mask[base + t] > 0.f) ? 1 : 0);
        flags |= is << i;
        c += is;
        prev = cur;
    }
    cnt[tid] = c;
    __syncthreads();
    for (int off = 1; off < 256; off <<= 1) {
        int add = (tid >= off) ? cnt[tid - off] : 0;
        __syncthreads();
        cnt[tid] += add;
        __syncthreads();
    }
    int pos = cnt[tid] - c;   // exclusive prefix
    #pragma unroll
    for (int i = 0; i < 16; ++i) {
        if ((flags >> i) & 1) selpos[base + pos++] = t0 + i;
    }
    if (tid == 255) nst[b] = cnt[255];

    // boundary smoothness pairs: (t, t+1) at t = 127 + j*128, j=0..30
    float v = 0.f;
    for (int e = tid; e < 31 * 64; e += 256) {
        const int j = e >> 6, cc = e & 63;
        const int t = j * 128 + 127;
        const int qq = base + t;
        const float d = zqo[(size_t)qq * C_ + cc] - zqo[(size_t)(qq + 1) * C_ + cc];
        v = fmaf(d * mask[qq + 1], d, v);
    }
    #pragma unroll
    for (int off = 32; off > 0; off >>= 1) v += __shfl_down(v, off);
    if ((tid & 63) == 0) sred[tid >> 6] = v;
    __syncthreads();
    if (tid == 0) smooth_part[512 + b] = sred[0] + sred[1] + sred[2] + sred[3];
}

// ---- fused n_z_q gather + n_mask + selected_encodings + loss finalize ----
__global__ __launch_bounds__(256) void k_gsel(const float* __restrict__ zqo,
                                              const int* __restrict__ kbest,
                                              const int* __restrict__ selpos,
                                              const int* __restrict__ nst,
                                              const float* __restrict__ commit_part,
                                              const float* __restrict__ valid_part,
                                              const float* __restrict__ smooth_part,
                                              float* __restrict__ nzq,
                                              float* __restrict__ nmask,
                                              float* __restrict__ sel,
                                              float* __restrict__ out) {
    const int gid = blockIdx.x * 256 + threadIdx.x;   // float4 index
    const int b   = gid >> 16;          // T*C/4 = 65536 float4 per batch
    const int rem = gid & 65535;
    const int j   = rem >> 4;
    const int c4  = rem & 15;
    const int n   = nst[b];
    float4 v = make_float4(0.f, 0.f, 0.f, 0.f);
    int p = 0;
    if (j < n) {
        p = selpos[b * T_ + j];
        v = ((const float4*)zqo)[((size_t)b * T_ + p) * 16 + c4];
    }
    ((float4*)nzq)[gid] = v;
    if (c4 == 0) {
        float nm = 0.f, s = 0.f;
        if (j < n) { nm = 1.f; s = (float)(kbest[b * T_ + p] + 1); }
        nmask[b * T_ + j] = nm;
        sel[b * T_ + j]   = s;
    }

    // loss finalize: one block (inputs ready since k_scan completed)
    if (blockIdx.x == 0) {
        __shared__ double rc[256];
        __shared__ double rv[256];
        __shared__ double rs[256];
        const int tid = threadIdx.x;
        double sc = (double)commit_part[tid] + (double)commit_part[tid + 256];
        double sv = (double)valid_part[tid]  + (double)valid_part[tid + 256];
        double ssm = (double)smooth_part[tid] + (double)smooth_part[tid + 256];
        if (tid < 16) ssm += (double)smooth_part[512 + tid];
        rc[tid] = sc; rv[tid] = sv; rs[tid] = ssm;
        __syncthreads();
        for (int off = 128; off > 0; off >>= 1) {
            if (tid < off) {
                rc[tid] += rc[tid + off];
                rv[tid] += rv[tid + off];
                rs[tid] += rs[tid + off];
            }
            __syncthreads();
        }
        if (tid == 0) {
            double valid = rv[0];
            out[0] = (float)(rs[0] / (valid - (double)B_));  // m1.sum() = valid - B
            out[1] = (float)(rc[0] / valid);
        }
    }
}

extern "C" void kernel_launch(void* const* d_in, const int* in_sizes, int n_in,
                              void* d_out, int out_size, void* d_ws, size_t ws_size,
                              hipStream_t stream) {
    const float* z    = (const float*)d_in[0];
    const float* cb   = (const float*)d_in[1];
    const float* mask = (const float*)d_in[2];
    float* out = (float*)d_out;
    char* ws = (char*)d_ws;

    float*          ee          = (float*)(ws + 64);
    unsigned short* Eh          = (unsigned short*)(ws + 4224);
    unsigned short* El          = (unsigned short*)(ws + 135296);
    int*            kbest       = (int*)(ws + 266368);
    int*            selpos      = (int*)(ws + 528512);
    int*            nst         = (int*)(ws + 790656);
    float*          commit_part = (float*)(ws + 791680);
    float*          valid_part  = (float*)(ws + 793728);
    float*          smooth_part = (float*)(ws + 795776);

    float* zqo   = out + 2;
    float* nzq   = zqo + (size_t)BT_ * C_;
    float* nmask = nzq + (size_t)BT_ * C_;
    float* sel   = nmask + BT_;

    k_prep  <<<4,    256, 0, stream>>>(cb, ee, Eh, El);
    k_assign<<<512,  256, 0, stream>>>(z, cb, Eh, El, ee, mask, kbest, zqo,
                                       commit_part, valid_part, smooth_part);
    k_scan  <<<B_,   256, 0, stream>>>(kbest, mask, zqo, selpos, nst, smooth_part);
    k_gsel  <<<4096, 256, 0, stream>>>(zqo, kbest, selpos, nst,
                                       commit_part, valid_part, smooth_part,
                                       nzq, nmask, sel, out);
}

// Round 10
// 156.212 us; speedup vs baseline: 1.2234x; 1.2234x over previous
//
#include <hip/hip_runtime.h>
#include <math.h>

typedef __attribute__((ext_vector_type(8))) short short8;
typedef __attribute__((ext_vector_type(4))) float f32x4;

#define B_  16
#define T_  4096
#define C_  64
#define KE_ 1023
#define BT_ (B_ * T_)
#define WINDOW 1e-3f   // guard band >= 3x provable bf16-split distance error

// ---------------- ws layout (bytes) ----------------
// [0,       64)      int   flagcnt
// [64,      4160)    float ee[1024]        (|e_k|^2, ee[1023]=+inf pad)
// [4224,    135296)  u16   Eh[1024*64]     (bf16 hi of codebook[1:])
// [135296,  266368)  u16   El[1024*64]     (bf16 lo residual)
// [266368,  528512)  int   kbest[BT]
// [528512,  790656)  int   selpos[BT]
// [790656,  790720)  int   nst[B]
// [791680,  792704)  float commit_part[256]
// [792704,  793728)  float valid_part[256]
// [793728,  794816)  float smooth_part[272]   (256 in-block + 16 boundary)
// [794816,  1056960) int   flaglist[BT]

__device__ __forceinline__ unsigned short f2bf(float x) {
    unsigned int u = __float_as_uint(x);
    unsigned int r = (u + 0x7FFFu + ((u >> 16) & 1u)) >> 16;   // RNE
    return (unsigned short)r;
}
__device__ __forceinline__ float bf2f(unsigned short h) {
    return __uint_as_float(((unsigned int)h) << 16);
}

// ---- prep: ee, bf16 hi/lo codebook, flagcnt=0 ----
__global__ __launch_bounds__(256) void k_prep(const float* __restrict__ cb,
                                              float* __restrict__ ee,
                                              unsigned short* __restrict__ Eh,
                                              unsigned short* __restrict__ El,
                                              int* __restrict__ flagcnt) {
    const int k = blockIdx.x * 256 + threadIdx.x;   // 0..1023
    if (k == 0) *flagcnt = 0;
    unsigned int* EhU = (unsigned int*)Eh;
    unsigned int* ElU = (unsigned int*)El;
    if (k < KE_) {
        const float* r = cb + (size_t)(k + 1) * C_;
        float s = 0.f;
        #pragma unroll
        for (int c = 0; c < C_; c += 2) {
            const float x0 = r[c], x1 = r[c + 1];
            s = fmaf(x0, x0, s);
            s = fmaf(x1, x1, s);
            const unsigned short h0 = f2bf(x0), h1 = f2bf(x1);
            const unsigned short l0 = f2bf(x0 - bf2f(h0));
            const unsigned short l1 = f2bf(x1 - bf2f(h1));
            EhU[k * 32 + c / 2] = (unsigned int)h0 | ((unsigned int)h1 << 16);
            ElU[k * 32 + c / 2] = (unsigned int)l0 | ((unsigned int)l1 << 16);
        }
        ee[k] = s;
    } else {        // k == 1023 pad: zero rows, inf distance
        #pragma unroll
        for (int c = 0; c < 32; ++c) { EhU[k * 32 + c] = 0u; ElU[k * 32 + c] = 0u; }
        ee[k] = INFINITY;
    }
}

// ---- hot kernel: bf16 hi/lo split MFMA + top-2 guard (verified R6/R7) ----
__global__ __launch_bounds__(256, 4) void k_assign(
    const float* __restrict__ z, const unsigned short* __restrict__ Eh,
    const unsigned short* __restrict__ El, const float* __restrict__ ee,
    int* __restrict__ kbest, int* __restrict__ flaglist,
    int* __restrict__ flagcnt) {

    __shared__ __align__(16) unsigned short s_eh[128 * 72];
    __shared__ __align__(16) unsigned short s_el[128 * 72];
    __shared__ float s_ee[128];

    const int tid  = threadIdx.x;
    const int wave = tid >> 6;
    const int lane = tid & 63;
    const int col  = lane & 15;
    const int quad = lane >> 4;
    const int Q0   = blockIdx.x * 128 + wave * 32;

    short8 ah[2][2], al[2][2];
    #pragma unroll
    for (int g = 0; g < 2; ++g) {
        const float4* zp = (const float4*)(z + (size_t)(Q0 + g * 16 + col) * C_);
        const float4 f0 = zp[quad * 2];
        const float4 f1 = zp[quad * 2 + 1];
        const float4 f2 = zp[8 + quad * 2];
        const float4 f3 = zp[8 + quad * 2 + 1];
        float xs[16] = {f0.x, f0.y, f0.z, f0.w, f1.x, f1.y, f1.z, f1.w,
                        f2.x, f2.y, f2.z, f2.w, f3.x, f3.y, f3.z, f3.w};
        float ss = 0.f;
        #pragma unroll
        for (int i = 0; i < 16; ++i) ss = fmaf(xs[i], xs[i], ss);
        ss += __shfl_xor(ss, 16);
        ss += __shfl_xor(ss, 32);
        const float inv = 1.f / fmaxf(sqrtf(ss), 1e-12f);
        short8 h0, h1, l0, l1;
        #pragma unroll
        for (int i = 0; i < 8; ++i) {
            const float x = xs[i] * inv;
            const unsigned short hx = f2bf(x);
            h0[i] = (short)hx;
            l0[i] = (short)f2bf(x - bf2f(hx));
            const float y = xs[8 + i] * inv;
            const unsigned short hy = f2bf(y);
            h1[i] = (short)hy;
            l1[i] = (short)f2bf(y - bf2f(hy));
        }
        ah[g][0] = h0; ah[g][1] = h1;
        al[g][0] = l0; al[g][1] = l1;
    }

    float bestv[2][4], secv[2][4];
    int   bkk[2][4];
    #pragma unroll
    for (int g = 0; g < 2; ++g)
        #pragma unroll
        for (int r = 0; r < 4; ++r) {
            bestv[g][r] = INFINITY; secv[g][r] = INFINITY; bkk[g][r] = 0;
        }

    for (int t = 0; t < 8; ++t) {
        __syncthreads();
        #pragma unroll
        for (int j = 0; j < 4; ++j) {
            const int p   = j * 256 + tid;
            const int row = p >> 3;
            const int pc  = p & 7;
            *(uint4*)(&s_eh[row * 72 + pc * 8]) =
                *(const uint4*)(&Eh[(size_t)(t * 128 + row) * 64 + pc * 8]);
            *(uint4*)(&s_el[row * 72 + pc * 8]) =
                *(const uint4*)(&El[(size_t)(t * 128 + row) * 64 + pc * 8]);
        }
        if (tid < 128) s_ee[tid] = ee[t * 128 + tid];
        __syncthreads();

        #pragma unroll 2
        for (int s = 0; s < 8; ++s) {
            const int rbase = (s * 16 + col) * 72 + quad * 8;
            const short8 bh0 = *(const short8*)(&s_eh[rbase]);
            const short8 bh1 = *(const short8*)(&s_eh[rbase + 32]);
            const short8 bl0 = *(const short8*)(&s_el[rbase]);
            const short8 bl1 = *(const short8*)(&s_el[rbase + 32]);
            const float  eev = s_ee[s * 16 + col];

            f32x4 p0 = {0.f, 0.f, 0.f, 0.f}, q0 = {0.f, 0.f, 0.f, 0.f};
            f32x4 p1 = {0.f, 0.f, 0.f, 0.f}, q1 = {0.f, 0.f, 0.f, 0.f};
            p0 = __builtin_amdgcn_mfma_f32_16x16x32_bf16(ah[0][0], bh0, p0, 0, 0, 0);
            p1 = __builtin_amdgcn_mfma_f32_16x16x32_bf16(ah[1][0], bh0, p1, 0, 0, 0);
            q0 = __builtin_amdgcn_mfma_f32_16x16x32_bf16(ah[0][1], bh1, q0, 0, 0, 0);
            q1 = __builtin_amdgcn_mfma_f32_16x16x32_bf16(ah[1][1], bh1, q1, 0, 0, 0);
            p0 = __builtin_amdgcn_mfma_f32_16x16x32_bf16(ah[0][0], bl0, p0, 0, 0, 0);
            p1 = __builtin_amdgcn_mfma_f32_16x16x32_bf16(ah[1][0], bl0, p1, 0, 0, 0);
            q0 = __builtin_amdgcn_mfma_f32_16x16x32_bf16(ah[0][1], bl1, q0, 0, 0, 0);
            q1 = __builtin_amdgcn_mfma_f32_16x16x32_bf16(ah[1][1], bl1, q1, 0, 0, 0);
            p0 = __builtin_amdgcn_mfma_f32_16x16x32_bf16(al[0][0], bh0, p0, 0, 0, 0);
            p1 = __builtin_amdgcn_mfma_f32_16x16x32_bf16(al[1][0], bh0, p1, 0, 0, 0);
            q0 = __builtin_amdgcn_mfma_f32_16x16x32_bf16(al[0][1], bh1, q0, 0, 0, 0);
            q1 = __builtin_amdgcn_mfma_f32_16x16x32_bf16(al[1][1], bh1, q1, 0, 0, 0);

            const int kc = t * 128 + s * 16 + col;
            #pragma unroll
            for (int r = 0; r < 4; ++r) {
                {
                    const float v = fmaf(-2.f, p0[r] + q0[r], eev);
                    const bool lt = v < bestv[0][r];
                    secv[0][r]  = lt ? bestv[0][r] : fminf(secv[0][r], v);
                    bkk[0][r]   = lt ? kc : bkk[0][r];
                    bestv[0][r] = lt ? v : bestv[0][r];
                }
                {
                    const float v = fmaf(-2.f, p1[r] + q1[r], eev);
                    const bool lt = v < bestv[1][r];
                    secv[1][r]  = lt ? bestv[1][r] : fminf(secv[1][r], v);
                    bkk[1][r]   = lt ? kc : bkk[1][r];
                    bestv[1][r] = lt ? v : bestv[1][r];
                }
            }
        }
    }

    #pragma unroll
    for (int g = 0; g < 2; ++g) {
        #pragma unroll
        for (int r = 0; r < 4; ++r) {
            float b  = bestv[g][r], sc = secv[g][r];
            int   k  = bkk[g][r];
            #pragma unroll
            for (int off = 1; off < 16; off <<= 1) {
                const float ob = __shfl_xor(b, off);
                const int   ok = __shfl_xor(k, off);
                const float os = __shfl_xor(sc, off);
                const bool take = (ob < b) || (ob == b && ok < k);
                const float lose = take ? b : ob;
                sc = fminf(fminf(sc, os), lose);
                b  = take ? ob : b;
                k  = take ? ok : k;
            }
            if (col == 0) {
                const int q = Q0 + g * 16 + quad * 4 + r;
                kbest[q] = k;
                if (!(sc - b > WINDOW)) {              // ambiguous -> exact path
                    const int pos = atomicAdd(flagcnt, 1);
                    flaglist[pos] = q;
                }
            }
        }
    }
}

// ---- exact fp32 rescan, BLOCK per flagged query (verified R7) ----
__global__ __launch_bounds__(256) void k_fix(const float* __restrict__ z,
                                             const float* __restrict__ cb,
                                             const float* __restrict__ ee,
                                             const int* __restrict__ flagcnt,
                                             const int* __restrict__ flaglist,
                                             int* __restrict__ kbest) {
    __shared__ float s_z[64];
    __shared__ float s_bv[4];
    __shared__ int   s_bk[4];
    const int tid  = threadIdx.x;
    const int lane = tid & 63;
    const int wave = tid >> 6;
    const int n = *flagcnt;

    for (int i = blockIdx.x; i < n; i += 1024) {
        const int q = flaglist[i];
        __syncthreads();               // s_z reuse guard across iterations
        if (tid < 16) ((float4*)s_z)[tid] = ((const float4*)(z + (size_t)q * C_))[tid];
        __syncthreads();

        float4 zn[16];
        float ss = 0.f;
        #pragma unroll
        for (int c4 = 0; c4 < 16; ++c4) {
            const float4 v = ((const float4*)s_z)[c4];
            zn[c4] = v;
            ss = fmaf(v.x, v.x, ss); ss = fmaf(v.y, v.y, ss);
            ss = fmaf(v.z, v.z, ss); ss = fmaf(v.w, v.w, ss);
        }
        const float nrm = fmaxf(sqrtf(ss), 1e-12f);
        #pragma unroll
        for (int c4 = 0; c4 < 16; ++c4) {
            zn[c4].x /= nrm; zn[c4].y /= nrm; zn[c4].z /= nrm; zn[c4].w /= nrm;
        }

        const int k0 = tid * 4;        // codes k0..k0+3 (k0+3 <= 1023)
        const float4* e0 = (const float4*)(cb + (size_t)(k0 + 1) * C_);
        const float4* e1 = (const float4*)(cb + (size_t)(k0 + 2) * C_);
        const float4* e2 = (const float4*)(cb + (size_t)(k0 + 3) * C_);
        const float4* e3 = (const float4*)(cb + (size_t)((k0 + 4 <= KE_) ? (k0 + 4) : KE_) * C_);
        float d0 = 0.f, d1 = 0.f, d2 = 0.f, d3 = 0.f;
        #pragma unroll
        for (int c4 = 0; c4 < 16; ++c4) {   // in-order fp32 chains
            const float4 x = zn[c4];
            const float4 a = e0[c4], b = e1[c4], c = e2[c4], d = e3[c4];
            d0 = fmaf(x.x, a.x, d0); d0 = fmaf(x.y, a.y, d0);
            d0 = fmaf(x.z, a.z, d0); d0 = fmaf(x.w, a.w, d0);
            d1 = fmaf(x.x, b.x, d1); d1 = fmaf(x.y, b.y, d1);
            d1 = fmaf(x.z, b.z, d1); d1 = fmaf(x.w, b.w, d1);
            d2 = fmaf(x.x, c.x, d2); d2 = fmaf(x.y, c.y, d2);
            d2 = fmaf(x.z, c.z, d2); d2 = fmaf(x.w, c.w, d2);
            d3 = fmaf(x.x, d.x, d3); d3 = fmaf(x.y, d.y, d3);
            d3 = fmaf(x.z, d.z, d3); d3 = fmaf(x.w, d.w, d3);
        }
        float bv = INFINITY;
        int   bk = 0;
        float v;
        v = fmaf(-2.f, d0, ee[k0 + 0]); if (v < bv) { bv = v; bk = k0 + 0; }
        v = fmaf(-2.f, d1, ee[k0 + 1]); if (v < bv) { bv = v; bk = k0 + 1; }
        v = fmaf(-2.f, d2, ee[k0 + 2]); if (v < bv) { bv = v; bk = k0 + 2; }
        v = fmaf(-2.f, d3, ee[k0 + 3]); if (v < bv) { bv = v; bk = k0 + 3; }

        #pragma unroll
        for (int off = 32; off > 0; off >>= 1) {
            const float ov = __shfl_down(bv, off);
            const int   ok = __shfl_down(bk, off);
            if (ov < bv || (ov == bv && ok < bk)) { bv = ov; bk = ok; }
        }
        if (lane == 0) { s_bv[wave] = bv; s_bk[wave] = bk; }
        __syncthreads();
        if (tid == 0) {
            float fb = s_bv[0]; int fk = s_bk[0];
            #pragma unroll
            for (int w = 1; w < 4; ++w) {
                if (s_bv[w] < fb || (s_bv[w] == fb && s_bk[w] < fk)) {
                    fb = s_bv[w]; fk = s_bk[w];
                }
            }
            kbest[q] = fk;
        }
    }
}

// ---- epilogue: z_q, commit/valid partials + wave-local smoothness ----
__global__ __launch_bounds__(256) void k_epi(
    const float* __restrict__ z, const float* __restrict__ cb,
    const float* __restrict__ mask, const int* __restrict__ kbest,
    float* __restrict__ zqo,
    float* __restrict__ commit_part, float* __restrict__ valid_part,
    float* __restrict__ smooth_part) {

    __shared__ float s_red[12];
    const int tid  = threadIdx.x;
    const int lane = tid & 63;
    const int wave = tid >> 6;
    const int q    = blockIdx.x * 256 + tid;

    const int bi = kbest[q];
    const float m     = mask[q];
    const float mnext = (lane != 63) ? mask[q + 1] : 0.f;

    const float4* zp = (const float4*)(z + (size_t)q * C_);
    const float4* er = (const float4*)(cb + (size_t)(bi + 1) * C_);
    float4* zo = (float4*)(zqo + (size_t)q * C_);

    float4 zr[16];
    float ss = 0.f;
    #pragma unroll
    for (int i = 0; i < 16; ++i) {
        float4 v = zp[i];
        zr[i] = v;
        ss = fmaf(v.x, v.x, ss); ss = fmaf(v.y, v.y, ss);
        ss = fmaf(v.z, v.z, ss); ss = fmaf(v.w, v.w, ss);
    }
    const float nrm = fmaxf(sqrtf(ss), 1e-12f);

    float commit = 0.f, sm = 0.f;
    #pragma unroll
    for (int c4 = 0; c4 < 16; ++c4) {
        const float z0 = zr[c4].x / nrm, z1 = zr[c4].y / nrm;
        const float z2 = zr[c4].z / nrm, z3 = zr[c4].w / nrm;
        const float4 e4 = er[c4];
        const float q0 = e4.x * m, q1 = e4.y * m, q2 = e4.z * m, q3 = e4.w * m;
        float4 o;
        o.x = (z0 + q0) - z0;              // straight-through forward value
        o.y = (z1 + q1) - z1;
        o.z = (z2 + q2) - z2;
        o.w = (z3 + q3) - z3;
        zo[c4] = o;
        const float d0 = z0 - q0, d1 = z1 - q1, d2 = z2 - q2, d3 = z3 - q3;
        commit = fmaf(d0, d0, commit); commit = fmaf(d1, d1, commit);
        commit = fmaf(d2, d2, commit); commit = fmaf(d3, d3, commit);
        // wave-local smoothness pair (q, q+1): neighbor regs via shfl
        const float n0 = __shfl_down(o.x, 1);
        const float n1 = __shfl_down(o.y, 1);
        const float n2 = __shfl_down(o.z, 1);
        const float n3 = __shfl_down(o.w, 1);
        const float x0 = o.x - n0, x1 = o.y - n1;
        const float x2 = o.z - n2, x3 = o.w - n3;
        sm = fmaf(x0, x0, sm); sm = fmaf(x1, x1, sm);
        sm = fmaf(x2, x2, sm); sm = fmaf(x3, x3, sm);
    }
    commit *= m;
    sm     *= mnext;
    float vc = m;
    #pragma unroll
    for (int off = 32; off > 0; off >>= 1) {
        commit += __shfl_down(commit, off);
        vc     += __shfl_down(vc, off);
        sm     += __shfl_down(sm, off);
    }
    if (lane == 0) { s_red[wave] = commit; s_red[4 + wave] = vc; s_red[8 + wave] = sm; }
    __syncthreads();
    if (tid == 0) {
        commit_part[blockIdx.x] = s_red[0] + s_red[1] + s_red[2] + s_red[3];
        valid_part[blockIdx.x]  = s_red[4] + s_red[5] + s_red[6] + s_red[7];
        smooth_part[blockIdx.x] = s_red[8] + s_red[9] + s_red[10] + s_red[11];
    }
}

// ---- per-batch start compaction + wave-boundary smoothness pairs ----
__global__ __launch_bounds__(256) void k_scan(const int* __restrict__ kbest,
                                              const float* __restrict__ mask,
                                              const float* __restrict__ zqo,
                                              int* __restrict__ selpos,
                                              int* __restrict__ nst,
                                              float* __restrict__ smooth_part) {
    __shared__ int cnt[256];
    __shared__ float sred[4];
    const int b = blockIdx.x;
    const int tid = threadIdx.x;
    const int base = b * T_;
    const int t0 = tid * 16;

    int flags = 0, c = 0;
    int prev = (tid == 0) ? -1 : kbest[base + t0 - 1];
    #pragma unroll
    for (int i = 0; i < 16; ++i) {
        const int t = t0 + i;
        const int cur = kbest[base + t];
        const int is = (t == 0) ? 1
                     : ((cur != prev && mask[base + t] > 0.f) ? 1 : 0);
        flags |= is << i;
        c += is;
        prev = cur;
    }
    cnt[tid] = c;
    __syncthreads();
    for (int off = 1; off < 256; off <<= 1) {
        int add = (tid >= off) ? cnt[tid - off] : 0;
        __syncthreads();
        cnt[tid] += add;
        __syncthreads();
    }
    int pos = cnt[tid] - c;   // exclusive prefix
    #pragma unroll
    for (int i = 0; i < 16; ++i) {
        if ((flags >> i) & 1) selpos[base + pos++] = t0 + i;
    }
    if (tid == 255) nst[b] = cnt[255];

    // boundary smoothness pairs: (t, t+1) at t = 63 + j*64, j=0..62
    float v = 0.f;
    for (int e = tid; e < 63 * 64; e += 256) {
        const int j = e >> 6, cc = e & 63;
        const int t = j * 64 + 63;
        const int qq = base + t;
        const float d = zqo[(size_t)qq * C_ + cc] - zqo[(size_t)(qq + 1) * C_ + cc];
        v = fmaf(d * mask[qq + 1], d, v);
    }
    #pragma unroll
    for (int off = 32; off > 0; off >>= 1) v += __shfl_down(v, off);
    if ((tid & 63) == 0) sred[tid >> 6] = v;
    __syncthreads();
    if (tid == 0) smooth_part[256 + b] = sred[0] + sred[1] + sred[2] + sred[3];
}

// ---- fused n_z_q gather + n_mask + selected_encodings + loss finalize ----
__global__ __launch_bounds__(256) void k_gsel(const float* __restrict__ zqo,
                                              const int* __restrict__ kbest,
                                              const int* __restrict__ selpos,
                                              const int* __restrict__ nst,
                                              const float* __restrict__ commit_part,
                                              const float* __restrict__ valid_part,
                                              const float* __restrict__ smooth_part,
                                              float* __restrict__ nzq,
                                              float* __restrict__ nmask,
                                              float* __restrict__ sel,
                                              float* __restrict__ out) {
    const int gid = blockIdx.x * 256 + threadIdx.x;   // float4 index
    const int b   = gid >> 16;          // T*C/4 = 65536 float4 per batch
    const int rem = gid & 65535;
    const int j   = rem >> 4;
    const int c4  = rem & 15;
    const int n   = nst[b];
    float4 v = make_float4(0.f, 0.f, 0.f, 0.f);
    int p = 0;
    if (j < n) {
        p = selpos[b * T_ + j];
        v = ((const float4*)zqo)[((size_t)b * T_ + p) * 16 + c4];
    }
    ((float4*)nzq)[gid] = v;
    if (c4 == 0) {
        float nm = 0.f, s = 0.f;
        if (j < n) { nm = 1.f; s = (float)(kbest[b * T_ + p] + 1); }
        nmask[b * T_ + j] = nm;
        sel[b * T_ + j]   = s;
    }

    // loss finalize: block 0 (partials ready: k_epi/k_scan precede this)
    if (blockIdx.x == 0) {
        __shared__ double rc[256];
        __shared__ double rv[256];
        __shared__ double rs[256];
        const int tid = threadIdx.x;
        double sc = (double)commit_part[tid];
        double sv = (double)valid_part[tid];
        double ssm = (double)smooth_part[tid];
        if (tid < 16) ssm += (double)smooth_part[256 + tid];
        rc[tid] = sc; rv[tid] = sv; rs[tid] = ssm;
        __syncthreads();
        for (int off = 128; off > 0; off >>= 1) {
            if (tid < off) {
                rc[tid] += rc[tid + off];
                rv[tid] += rv[tid + off];
                rs[tid] += rs[tid + off];
            }
            __syncthreads();
        }
        if (tid == 0) {
            double valid = rv[0];
            out[0] = (float)(rs[0] / (valid - (double)B_));  // m1.sum() = valid - B
            out[1] = (float)(rc[0] / valid);
        }
    }
}

extern "C" void kernel_launch(void* const* d_in, const int* in_sizes, int n_in,
                              void* d_out, int out_size, void* d_ws, size_t ws_size,
                              hipStream_t stream) {
    const float* z    = (const float*)d_in[0];
    const float* cb   = (const float*)d_in[1];
    const float* mask = (const float*)d_in[2];
    float* out = (float*)d_out;
    char* ws = (char*)d_ws;

    int*            flagcnt     = (int*)(ws + 0);
    float*          ee          = (float*)(ws + 64);
    unsigned short* Eh          = (unsigned short*)(ws + 4224);
    unsigned short* El          = (unsigned short*)(ws + 135296);
    int*            kbest       = (int*)(ws + 266368);
    int*            selpos      = (int*)(ws + 528512);
    int*            nst         = (int*)(ws + 790656);
    float*          commit_part = (float*)(ws + 791680);
    float*          valid_part  = (float*)(ws + 792704);
    float*          smooth_part = (float*)(ws + 793728);
    int*            flaglist    = (int*)(ws + 794816);

    float* zqo   = out + 2;
    float* nzq   = zqo + (size_t)BT_ * C_;
    float* nmask = nzq + (size_t)BT_ * C_;
    float* sel   = nmask + BT_;

    k_prep  <<<4,    256, 0, stream>>>(cb, ee, Eh, El, flagcnt);
    k_assign<<<512,  256, 0, stream>>>(z, Eh, El, ee, kbest, flaglist, flagcnt);
    k_fix   <<<1024, 256, 0, stream>>>(z, cb, ee, flagcnt, flaglist, kbest);
    k_epi   <<<256,  256, 0, stream>>>(z, cb, mask, kbest, zqo,
                                       commit_part, valid_part, smooth_part);
    k_scan  <<<B_,   256, 0, stream>>>(kbest, mask, zqo, selpos, nst, smooth_part);
    k_gsel  <<<4096, 256, 0, stream>>>(zqo, kbest, selpos, nst,
                                       commit_part, valid_part, smooth_part,
                                       nzq, nmask, sel, out);
}